// Round 1
// baseline (3775.603 us; speedup 1.0000x reference)
//
#include <hip/hip_runtime.h>

// ---------------- problem constants ----------------
constexpr int kB = 128, kP = 196, kT = 20;
constexpr int kVocab = 10000, kEnc = 2048, kEmb = 512, kDec = 512, kAttn = 512;

typedef __bf16 b16x8 __attribute__((ext_vector_type(8)));
typedef float f32x4 __attribute__((ext_vector_type(4)));
typedef unsigned short u16x4 __attribute__((ext_vector_type(4)));

__device__ __forceinline__ unsigned short f2bf(float f) {
  unsigned int u = __float_as_uint(f);
  u += 0x7fffu + ((u >> 16) & 1u);          // round-to-nearest-even (inputs finite)
  return (unsigned short)(u >> 16);
}
__device__ __forceinline__ float bf2f(unsigned short h) {
  return __uint_as_float(((unsigned int)h) << 16);
}

// ---------------- generic bf16 MFMA GEMM:  C[M,N] = A[M,K] @ W[N,K]^T + bias ----------------
// block = 256 thr = 4 waves in 2x2; wave = 32x32 tile = 2x2 mfma_16x16x32
// grid = (ceil(N/64), ceil(M/64)).  K % 32 == 0.  Rows clamped, stores guarded.
template <bool A_BF16, bool OUT_BF16>
__global__ __launch_bounds__(256) void gemm_bt(
    const void* __restrict__ A_, const unsigned short* __restrict__ W,
    const float* __restrict__ bias, float* __restrict__ C,
    unsigned short* __restrict__ Cb, int M, int N, int K, long ldc) {
  const int lane = threadIdx.x & 63;
  const int wave = threadIdx.x >> 6;
  const int wm = wave >> 1, wn = wave & 1;
  const int m0 = blockIdx.y * 64 + wm * 32;
  const int n0 = blockIdx.x * 64 + wn * 32;
  const int q = lane >> 4;       // quad 0..3
  const int l = lane & 15;
  f32x4 acc[2][2] = {};
  const unsigned short* Ab = (const unsigned short*)A_;
  const float* Af = (const float*)A_;

  for (int k0 = 0; k0 < K; k0 += 32) {
    const int ka = k0 + q * 8;
    b16x8 af[2], wf[2];
#pragma unroll
    for (int i = 0; i < 2; i++) {
      int r = m0 + 16 * i + l;
      if (r >= M) r = M - 1;
      if (A_BF16) {
        af[i] = *(const b16x8*)(Ab + (long)r * K + ka);
      } else {
        const float* p = Af + (long)r * K + ka;
        const f32x4 lo = *(const f32x4*)p;
        const f32x4 hi = *(const f32x4*)(p + 4);
        b16x8 t;
#pragma unroll
        for (int j = 0; j < 4; j++) {
          ((unsigned short*)&t)[j] = f2bf(lo[j]);
          ((unsigned short*)&t)[4 + j] = f2bf(hi[j]);
        }
        af[i] = t;
      }
    }
#pragma unroll
    for (int j = 0; j < 2; j++) {
      int r = n0 + 16 * j + l;
      if (r >= N) r = N - 1;
      wf[j] = *(const b16x8*)(W + (long)r * K + ka);
    }
#pragma unroll
    for (int i = 0; i < 2; i++)
#pragma unroll
      for (int j = 0; j < 2; j++)
        acc[i][j] = __builtin_amdgcn_mfma_f32_16x16x32_bf16(af[i], wf[j], acc[i][j], 0, 0, 0);
  }

#pragma unroll
  for (int i = 0; i < 2; i++) {
#pragma unroll
    for (int j = 0; j < 2; j++) {
      const int col = n0 + 16 * j + l;
      if (col >= N) continue;
      const float bv = bias ? bias[col] : 0.0f;
#pragma unroll
      for (int r = 0; r < 4; r++) {
        const int row = m0 + 16 * i + q * 4 + r;   // C/D: col=lane&15, row=quad*4+reg
        if (row >= M) continue;
        const float v = acc[i][j][r] + bv;
        if (OUT_BF16) Cb[(long)row * ldc + col] = f2bf(v);
        else          C[(long)row * ldc + col] = v;
      }
    }
  }
}

// ---------------- gates GEMM: [128,2048] = [emb|ctx|h][128,3072] @ [Wih|Whh]^T + (b_ih+b_hh) ----
// segment boundaries (512, 2560) are multiples of 32 -> k0-uniform source select
__global__ __launch_bounds__(256) void gemm_gates(
    const unsigned short* __restrict__ embs_t, const unsigned short* __restrict__ ctx,
    const unsigned short* __restrict__ hbf, const unsigned short* __restrict__ Wih,
    const unsigned short* __restrict__ Whh, const float* __restrict__ bias,
    float* __restrict__ gates) {
  const int lane = threadIdx.x & 63;
  const int wave = threadIdx.x >> 6;
  const int wm = wave >> 1, wn = wave & 1;
  const int m0 = blockIdx.y * 64 + wm * 32;   // M=128
  const int n0 = blockIdx.x * 64 + wn * 32;   // N=2048
  const int q = lane >> 4;
  const int l = lane & 15;
  f32x4 acc[2][2] = {};

  for (int k0 = 0; k0 < 3072; k0 += 32) {
    b16x8 af[2], wf[2];
#pragma unroll
    for (int i = 0; i < 2; i++) {
      const int r = m0 + 16 * i + l;          // < 128 always
      const unsigned short* p;
      if (k0 < 512)        p = embs_t + (long)r * kEmb + k0;
      else if (k0 < 2560)  p = ctx + (long)r * kEnc + (k0 - 512);
      else                 p = hbf + (long)r * kDec + (k0 - 2560);
      af[i] = *(const b16x8*)(p + q * 8);
    }
#pragma unroll
    for (int j = 0; j < 2; j++) {
      const int r = n0 + 16 * j + l;          // < 2048 always
      const unsigned short* p;
      if (k0 < 2560) p = Wih + (long)r * 2560 + k0;
      else           p = Whh + (long)r * 512 + (k0 - 2560);
      wf[j] = *(const b16x8*)(p + q * 8);
    }
#pragma unroll
    for (int i = 0; i < 2; i++)
#pragma unroll
      for (int j = 0; j < 2; j++)
        acc[i][j] = __builtin_amdgcn_mfma_f32_16x16x32_bf16(af[i], wf[j], acc[i][j], 0, 0, 0);
  }
#pragma unroll
  for (int i = 0; i < 2; i++)
#pragma unroll
    for (int j = 0; j < 2; j++) {
      const int col = n0 + 16 * j + l;
      const float bv = bias[col];
#pragma unroll
      for (int r = 0; r < 4; r++) {
        const int row = m0 + 16 * i + q * 4 + r;
        gates[(long)row * 2048 + col] = acc[i][j][r] + bv;
      }
    }
}

// ---------------- fused energy + softmax (one block per batch row) ----------------
__global__ __launch_bounds__(256) void energy_softmax(
    const unsigned short* __restrict__ attn_enc, const float* __restrict__ attn_dec,
    const float* __restrict__ fw, const float* __restrict__ fb,
    float* __restrict__ alphas, int t) {
  const int b = blockIdx.x;
  const int tid = threadIdx.x;
  const int lane = tid & 63, wave = tid >> 6;
  __shared__ float e_sm[kP];
  __shared__ float red[4], red2[4];

  float ad[8], w8[8];
  const int a0 = lane * 8;
#pragma unroll
  for (int j = 0; j < 8; j++) {
    ad[j] = attn_dec[b * kAttn + a0 + j];
    w8[j] = fw[a0 + j];
  }
  const float fb0 = fb[0];

  for (int p = wave; p < kP; p += 4) {
    const b16x8 rv = *(const b16x8*)(attn_enc + ((long)(b * kP + p)) * kAttn + a0);
    float s = 0.f;
#pragma unroll
    for (int j = 0; j < 8; j++) {
      const float v = bf2f(((const unsigned short*)&rv)[j]) + ad[j];
      s += w8[j] * fmaxf(v, 0.f);
    }
#pragma unroll
    for (int off = 32; off > 0; off >>= 1) s += __shfl_down(s, off, 64);
    if (lane == 0) e_sm[p] = s + fb0;
  }
  __syncthreads();

  const float v = (tid < kP) ? e_sm[tid] : -3.0e38f;
  float m = v;
#pragma unroll
  for (int off = 32; off > 0; off >>= 1) m = fmaxf(m, __shfl_down(m, off, 64));
  if (lane == 0) red[wave] = m;
  __syncthreads();
  m = fmaxf(fmaxf(red[0], red[1]), fmaxf(red[2], red[3]));

  const float ex = (tid < kP) ? expf(v - m) : 0.f;
  float s = ex;
#pragma unroll
  for (int off = 32; off > 0; off >>= 1) s += __shfl_down(s, off, 64);
  if (lane == 0) red2[wave] = s;
  __syncthreads();
  s = red2[0] + red2[1] + red2[2] + red2[3];

  if (tid < kP) alphas[((long)b * kT + t) * kP + tid] = ex / s;
}

// ---------------- context = alpha-weighted sum over P of encoder_out ----------------
template <bool SRC_BF16>
__global__ __launch_bounds__(256) void context_kernel(
    const void* __restrict__ enc_, const float* __restrict__ alphas, int t,
    unsigned short* __restrict__ ctx) {
  const int b = blockIdx.x;
  const int e = blockIdx.y * 512 + threadIdx.x * 2;   // grid.y = 4
  __shared__ float al[kP];
  for (int p = threadIdx.x; p < kP; p += 256)
    al[p] = alphas[((long)b * kT + t) * kP + p];
  __syncthreads();

  float a0 = 0.f, a1 = 0.f;
  if (SRC_BF16) {
    const unsigned short* base = (const unsigned short*)enc_ + (long)b * kP * kEnc + e;
    for (int p = 0; p < kP; p++) {
      const unsigned int u = *(const unsigned int*)(base + (long)p * kEnc);
      const float a = al[p];
      a0 += a * bf2f((unsigned short)(u & 0xffffu));
      a1 += a * bf2f((unsigned short)(u >> 16));
    }
  } else {
    const float* base = (const float*)enc_ + (long)b * kP * kEnc + e;
    for (int p = 0; p < kP; p++) {
      const float a = al[p];
      a0 += a * base[(long)p * kEnc];
      a1 += a * base[(long)p * kEnc + 1];
    }
  }
  const unsigned int packed = (unsigned int)f2bf(a0) | ((unsigned int)f2bf(a1) << 16);
  *(unsigned int*)(ctx + (long)b * kEnc + e) = packed;
}

// ---------------- LSTM pointwise ----------------
__global__ __launch_bounds__(256) void lstm_pw(
    const float* __restrict__ gates, float* __restrict__ c, float* __restrict__ h,
    unsigned short* __restrict__ hbf) {
  const int idx = blockIdx.x * 256 + threadIdx.x;  // 0 .. 128*512-1
  const int b = idx >> 9, d = idx & 511;
  const float gi = gates[(long)b * 2048 + d];
  const float gf = gates[(long)b * 2048 + 512 + d];
  const float gg = gates[(long)b * 2048 + 1024 + d];
  const float go = gates[(long)b * 2048 + 1536 + d];
  const float si = 1.f / (1.f + expf(-gi));
  const float sf = 1.f / (1.f + expf(-gf));
  const float so = 1.f / (1.f + expf(-go));
  const float cn = sf * c[idx] + si * tanhf(gg);
  const float hn = so * tanhf(cn);
  c[idx] = cn;
  h[idx] = hn;
  hbf[idx] = f2bf(hn);
}

// ---------------- mean over P of encoder_out (fp32 source) ----------------
__global__ __launch_bounds__(256) void mean_kernel(
    const float* __restrict__ enc, unsigned short* __restrict__ mean_bf) {
  const int b = blockIdx.x;
  const int e = threadIdx.x * 8;
  const float* base = enc + (long)b * kP * kEnc + e;
  float acc[8] = {};
  for (int p = 0; p < kP; p++) {
    const f32x4 lo = *(const f32x4*)(base + (long)p * kEnc);
    const f32x4 hi = *(const f32x4*)(base + (long)p * kEnc + 4);
#pragma unroll
    for (int j = 0; j < 4; j++) { acc[j] += lo[j]; acc[4 + j] += hi[j]; }
  }
#pragma unroll
  for (int j = 0; j < 8; j++)
    mean_bf[(long)b * kEnc + e + j] = f2bf(acc[j] * (1.0f / 196.0f));
}

// ---------------- fp32 -> bf16 bulk convert (n % 4 == 0) ----------------
__global__ __launch_bounds__(256) void f32_to_bf16_vec(
    const float* __restrict__ src, unsigned short* __restrict__ dst, long n4) {
  for (long i = blockIdx.x * (long)blockDim.x + threadIdx.x; i < n4;
       i += (long)gridDim.x * blockDim.x) {
    const f32x4 v = *(const f32x4*)(src + i * 4);
    u16x4 o;
#pragma unroll
    for (int j = 0; j < 4; j++) o[j] = f2bf(v[j]);
    *(u16x4*)(dst + i * 4) = o;
  }
}

// ---------------- embedding gather (+convert) ----------------
__global__ __launch_bounds__(256) void gather_emb(
    const float* __restrict__ embedding, const int* __restrict__ captions,
    unsigned short* __restrict__ embs) {
  const int r = blockIdx.x;           // t*128 + b
  const int t = r >> 7, b = r & 127;
  const int cap = captions[b * kT + t];
  const float* src = embedding + (long)cap * kEmb;
  unsigned short* dst = embs + (long)r * kEmb;
  for (int i = threadIdx.x; i < kEmb; i += 256) dst[i] = f2bf(src[i]);
}

__global__ void bias_sum_k(const float* __restrict__ b1, const float* __restrict__ b2,
                           float* __restrict__ o) {
  const int i = blockIdx.x * 256 + threadIdx.x;
  if (i < 2048) o[i] = b1[i] + b2[i];
}

// ---------------- host ----------------
extern "C" void kernel_launch(void* const* d_in, const int* in_sizes, int n_in,
                              void* d_out, int out_size, void* d_ws, size_t ws_size,
                              hipStream_t stream) {
  const float* enc = (const float*)d_in[0];
  const int* captions = (const int*)d_in[1];
  // d_in[2] = lengths (unused by reference)
  const float* embedding = (const float*)d_in[3];
  const float* eaw = (const float*)d_in[4];
  const float* eab = (const float*)d_in[5];
  const float* daw = (const float*)d_in[6];
  const float* dab = (const float*)d_in[7];
  const float* faw = (const float*)d_in[8];
  const float* fab = (const float*)d_in[9];
  const float* Wih = (const float*)d_in[10];
  const float* bih = (const float*)d_in[11];
  const float* Whh = (const float*)d_in[12];
  const float* bhh = (const float*)d_in[13];
  const float* ihw = (const float*)d_in[14];
  const float* ihb = (const float*)d_in[15];
  const float* icw = (const float*)d_in[16];
  const float* icb = (const float*)d_in[17];
  const float* fcw = (const float*)d_in[18];
  const float* fcb = (const float*)d_in[19];

  float* out = (float*)d_out;                        // outputs [B,T,VOCAB]
  float* alphas = out + (long)kB * kT * kVocab;      // alphas  [B,T,P]

  // ---- workspace layout (256B aligned). enc_bf16 LAST so we can drop it if ws too small.
  char* ws = (char*)d_ws;
  size_t off = 0;
  auto alloc = [&](size_t bytes) -> void* {
    void* p = ws + off;
    off = (off + bytes + 255) & ~(size_t)255;
    return p;
  };
  unsigned short* attn_enc_bf = (unsigned short*)alloc((size_t)kB * kP * kAttn * 2);
  unsigned short* Wih_bf = (unsigned short*)alloc((size_t)2048 * 2560 * 2);
  unsigned short* Whh_bf = (unsigned short*)alloc((size_t)2048 * 512 * 2);
  unsigned short* fcw_bf = (unsigned short*)alloc((size_t)kVocab * kDec * 2);
  unsigned short* eaw_bf = (unsigned short*)alloc((size_t)kAttn * kEnc * 2);
  unsigned short* daw_bf = (unsigned short*)alloc((size_t)kAttn * kDec * 2);
  unsigned short* ihw_bf = (unsigned short*)alloc((size_t)kDec * kEnc * 2);
  unsigned short* icw_bf = (unsigned short*)alloc((size_t)kDec * kEnc * 2);
  unsigned short* embs_bf = (unsigned short*)alloc((size_t)kT * kB * kEmb * 2);
  unsigned short* mean_bf = (unsigned short*)alloc((size_t)kB * kEnc * 2);
  float* h = (float*)alloc((size_t)kB * kDec * 4);
  float* c = (float*)alloc((size_t)kB * kDec * 4);
  unsigned short* h_bf = (unsigned short*)alloc((size_t)kB * kDec * 2);
  float* attn_dec = (float*)alloc((size_t)kB * kAttn * 4);
  unsigned short* ctx_bf = (unsigned short*)alloc((size_t)kB * kEnc * 2);
  float* gates = (float*)alloc((size_t)kB * 2048 * 4);
  float* bsum = (float*)alloc((size_t)2048 * 4);
  unsigned short* enc_bf = (unsigned short*)alloc((size_t)kB * kP * kEnc * 2);
  const bool have_enc_bf = (off <= ws_size);   // ~164 MB full / ~61 MB fallback

  auto cvt = [&](const float* s, unsigned short* d, long n) {
    const long n4 = n / 4;
    long g = (n4 + 255) / 256;
    if (g > 2048) g = 2048;
    f32_to_bf16_vec<<<dim3((unsigned)g), dim3(256), 0, stream>>>(s, d, n4);
  };

  // ---- prelude: converts, gather, mean, init h/c, attn_enc projection
  cvt(eaw, eaw_bf, (long)kAttn * kEnc);
  cvt(daw, daw_bf, (long)kAttn * kDec);
  cvt(Wih, Wih_bf, (long)2048 * 2560);
  cvt(Whh, Whh_bf, (long)2048 * 512);
  cvt(fcw, fcw_bf, (long)kVocab * kDec);
  cvt(ihw, ihw_bf, (long)kDec * kEnc);
  cvt(icw, icw_bf, (long)kDec * kEnc);
  if (have_enc_bf) cvt(enc, enc_bf, (long)kB * kP * kEnc);
  bias_sum_k<<<8, 256, 0, stream>>>(bih, bhh, bsum);
  gather_emb<<<kT * kB, 256, 0, stream>>>(embedding, captions, embs_bf);
  mean_kernel<<<kB, 256, 0, stream>>>(enc, mean_bf);

  gemm_bt<true, false><<<dim3(kDec / 64, kB / 64), 256, 0, stream>>>(
      mean_bf, ihw_bf, ihb, h, (unsigned short*)nullptr, kB, kDec, kEnc, kDec);
  gemm_bt<true, false><<<dim3(kDec / 64, kB / 64), 256, 0, stream>>>(
      mean_bf, icw_bf, icb, c, (unsigned short*)nullptr, kB, kDec, kEnc, kDec);
  cvt(h, h_bf, (long)kB * kDec);

  if (have_enc_bf)
    gemm_bt<true, true><<<dim3(kAttn / 64, (kB * kP) / 64), 256, 0, stream>>>(
        enc_bf, eaw_bf, eab, (float*)nullptr, attn_enc_bf, kB * kP, kAttn, kEnc, kAttn);
  else
    gemm_bt<false, true><<<dim3(kAttn / 64, (kB * kP) / 64), 256, 0, stream>>>(
        enc, eaw_bf, eab, (float*)nullptr, attn_enc_bf, kB * kP, kAttn, kEnc, kAttn);

  // ---- T sequential decode steps
  for (int t = 0; t < kT; t++) {
    // attn_dec = h @ dec_attn_w^T + b   [128,512]
    gemm_bt<true, false><<<dim3(kAttn / 64, kB / 64), 256, 0, stream>>>(
        h_bf, daw_bf, dab, attn_dec, (unsigned short*)nullptr, kB, kAttn, kDec, kAttn);
    // energy + softmax -> alphas[:, t, :]
    energy_softmax<<<kB, 256, 0, stream>>>(attn_enc_bf, attn_dec, faw, fab, alphas, t);
    // context
    if (have_enc_bf)
      context_kernel<true><<<dim3(kB, 4), 256, 0, stream>>>(enc_bf, alphas, t, ctx_bf);
    else
      context_kernel<false><<<dim3(kB, 4), 256, 0, stream>>>(enc, alphas, t, ctx_bf);
    // gates = [emb|ctx|h] @ [Wih|Whh]^T + (b_ih+b_hh)
    gemm_gates<<<dim3(2048 / 64, kB / 64), 256, 0, stream>>>(
        embs_bf + (long)t * kB * kEmb, ctx_bf, h_bf, Wih_bf, Whh_bf, bsum, gates);
    // LSTM pointwise -> h, c, h_bf
    lstm_pw<<<(kB * kDec) / 256, 256, 0, stream>>>(gates, c, h, h_bf);
    // preds = h_new @ fc_w^T + fc_b -> outputs[:, t, :]
    gemm_bt<true, false><<<dim3((kVocab + 63) / 64, kB / 64), 256, 0, stream>>>(
        h_bf, fcw_bf, fcb, out + (long)t * kVocab, (unsigned short*)nullptr,
        kB, kVocab, kDec, (long)kT * kVocab);
  }
}

// Round 2
// 2522.990 us; speedup vs baseline: 1.4965x; 1.4965x over previous
//
#include <hip/hip_runtime.h>

// ---------------- problem constants ----------------
constexpr int kB = 128, kP = 196, kT = 20;
constexpr int kVocab = 10000, kEnc = 2048, kEmb = 512, kDec = 512, kAttn = 512;

typedef __bf16 b16x8 __attribute__((ext_vector_type(8)));
typedef __bf16 b16x4 __attribute__((ext_vector_type(4)));
typedef float f32x4 __attribute__((ext_vector_type(4)));
typedef unsigned short u16x4 __attribute__((ext_vector_type(4)));

__device__ __forceinline__ unsigned short f2bf(float f) {
  unsigned int u = __float_as_uint(f);
  u += 0x7fffu + ((u >> 16) & 1u);          // RNE (inputs finite)
  return (unsigned short)(u >> 16);
}
__device__ __forceinline__ float bf2f(unsigned short h) {
  return __uint_as_float(((unsigned int)h) << 16);
}

__device__ __forceinline__ void async16(const void* g, void* l) {
  __builtin_amdgcn_global_load_lds(
      (const __attribute__((address_space(1))) unsigned int*)g,
      (__attribute__((address_space(3))) unsigned int*)l, 16, 0, 0);
}

// =========== LDS-tiled bf16 GEMM (m97 style): C[M,N] = A[M,K]@W[N,K]^T + bias ===========
// 128x128 tile, BK=32, 256 thr = 4 waves (2x2), wave=64x64 (4x4 mfma_16x16x32).
// Requires M%128==0, N%128==0, K%32==0. grid = (N/128, M/128).
template <bool OUT_BF16>
__global__ __launch_bounds__(256) void gemm128(
    const unsigned short* __restrict__ A, const unsigned short* __restrict__ W,
    const float* __restrict__ bias, float* __restrict__ C,
    unsigned short* __restrict__ Cb, int M, int N, int K, long ldc) {
  __shared__ unsigned short sA[128 * 32];
  __shared__ unsigned short sB[128 * 32];
  const int tid = threadIdx.x;
  const int lane = tid & 63;
  const int wave = tid >> 6;
  const int wm = wave >> 1, wn = wave & 1;
  const int m0 = blockIdx.y * 128;
  const int n0 = blockIdx.x * 128;
  const int q = lane >> 4, l = lane & 15;

  const int srow = tid >> 2;            // 0..63
  const int skk = (tid & 3) * 8;        // 0,8,16,24
  f32x4 acc[4][4] = {};

  for (int k0 = 0; k0 < K; k0 += 32) {
#pragma unroll
    for (int g = 0; g < 2; g++) {
      const int r = g * 64 + srow;
      async16(A + (long)(m0 + r) * K + k0 + skk, &sA[r * 32 + skk]);
      async16(W + (long)(n0 + r) * K + k0 + skk, &sB[r * 32 + skk]);
    }
    __syncthreads();
    b16x8 af[4], bf[4];
#pragma unroll
    for (int i = 0; i < 4; i++) {
      af[i] = *(const b16x8*)&sA[(wm * 64 + 16 * i + l) * 32 + q * 8];
      bf[i] = *(const b16x8*)&sB[(wn * 64 + 16 * i + l) * 32 + q * 8];
    }
#pragma unroll
    for (int i = 0; i < 4; i++)
#pragma unroll
      for (int j = 0; j < 4; j++)
        acc[i][j] = __builtin_amdgcn_mfma_f32_16x16x32_bf16(af[i], bf[j], acc[i][j], 0, 0, 0);
    __syncthreads();
  }

#pragma unroll
  for (int i = 0; i < 4; i++)
#pragma unroll
    for (int j = 0; j < 4; j++) {
      const int col = n0 + wn * 64 + 16 * j + l;
      const float bv = bias ? bias[col] : 0.0f;
#pragma unroll
      for (int r = 0; r < 4; r++) {
        const int row = m0 + wm * 64 + 16 * i + q * 4 + r;
        const float v = acc[i][j][r] + bv;
        if (OUT_BF16) Cb[(long)row * ldc + col] = f2bf(v);
        else          C[(long)row * ldc + col] = v;
      }
    }
}

// =========== generic small bf16 MFMA GEMM (64x64 tile, direct loads) ===========
template <bool A_BF16, bool OUT_BF16>
__global__ __launch_bounds__(256) void gemm_bt(
    const void* __restrict__ A_, const unsigned short* __restrict__ W,
    const float* __restrict__ bias, float* __restrict__ C,
    unsigned short* __restrict__ Cb, int M, int N, int K, long ldc) {
  const int lane = threadIdx.x & 63;
  const int wave = threadIdx.x >> 6;
  const int wm = wave >> 1, wn = wave & 1;
  const int m0 = blockIdx.y * 64 + wm * 32;
  const int n0 = blockIdx.x * 64 + wn * 32;
  const int q = lane >> 4;
  const int l = lane & 15;
  f32x4 acc[2][2] = {};
  const unsigned short* Ab = (const unsigned short*)A_;
  const float* Af = (const float*)A_;

  for (int k0 = 0; k0 < K; k0 += 32) {
    const int ka = k0 + q * 8;
    b16x8 af[2], wf[2];
#pragma unroll
    for (int i = 0; i < 2; i++) {
      int r = m0 + 16 * i + l;
      if (r >= M) r = M - 1;
      if (A_BF16) {
        af[i] = *(const b16x8*)(Ab + (long)r * K + ka);
      } else {
        const float* p = Af + (long)r * K + ka;
        const f32x4 lo = *(const f32x4*)p;
        const f32x4 hi = *(const f32x4*)(p + 4);
        b16x8 t;
#pragma unroll
        for (int j = 0; j < 4; j++) {
          ((unsigned short*)&t)[j] = f2bf(lo[j]);
          ((unsigned short*)&t)[4 + j] = f2bf(hi[j]);
        }
        af[i] = t;
      }
    }
#pragma unroll
    for (int j = 0; j < 2; j++) {
      int r = n0 + 16 * j + l;
      if (r >= N) r = N - 1;
      wf[j] = *(const b16x8*)(W + (long)r * K + ka);
    }
#pragma unroll
    for (int i = 0; i < 2; i++)
#pragma unroll
      for (int j = 0; j < 2; j++)
        acc[i][j] = __builtin_amdgcn_mfma_f32_16x16x32_bf16(af[i], wf[j], acc[i][j], 0, 0, 0);
  }

#pragma unroll
  for (int i = 0; i < 2; i++)
#pragma unroll
    for (int j = 0; j < 2; j++) {
      const int col = n0 + 16 * j + l;
      if (col >= N) continue;
      const float bv = bias ? bias[col] : 0.0f;
#pragma unroll
      for (int r = 0; r < 4; r++) {
        const int row = m0 + 16 * i + q * 4 + r;
        if (row >= M) continue;
        const float v = acc[i][j][r] + bv;
        if (OUT_BF16) Cb[(long)row * ldc + col] = f2bf(v);
        else          C[(long)row * ldc + col] = v;
      }
    }
}

// =========== fused attention step: attn_dec matvec + energy + softmax + context ===========
// grid (kB, 2): y-half duplicates ad/energy/softmax; splits the 2048-dim context read.
template <bool SRC_BF16>
__global__ __launch_bounds__(256) void attn_step(
    const void* __restrict__ enc_, const unsigned short* __restrict__ attn_enc_bf,
    const unsigned short* __restrict__ h_bf, const unsigned short* __restrict__ daw_bf,
    const float* __restrict__ dab, const float* __restrict__ faw, const float* __restrict__ fab,
    float* __restrict__ alphas, unsigned short* __restrict__ ctx, int t) {
  const int b = blockIdx.x;
  const int half = blockIdx.y;
  const int tid = threadIdx.x;
  const int lane = tid & 63, wave = tid >> 6;
  __shared__ float h_s[512];
  __shared__ float ad_s[512];
  __shared__ float e_sm[kP];
  __shared__ float red[4];

  // h -> LDS (fp32)
  h_s[tid] = bf2f(h_bf[b * kDec + tid]);
  h_s[tid + 256] = bf2f(h_bf[b * kDec + tid + 256]);
  __syncthreads();

  // ad[j] = h . daw[j,:] + dab[j]   (2 cols per thread, fp32 accum)
#pragma unroll
  for (int cc = 0; cc < 2; cc++) {
    const int j = tid + cc * 256;
    float s = dab[j];
    const unsigned short* wrow = daw_bf + (long)j * kDec;
    for (int k = 0; k < kDec; k += 8) {
      const b16x8 wv = *(const b16x8*)(wrow + k);
#pragma unroll
      for (int jj = 0; jj < 8; jj++)
        s += bf2f(((const unsigned short*)&wv)[jj]) * h_s[k + jj];
    }
    ad_s[j] = s;
  }
  __syncthreads();

  // energy[p] = fw . relu(attn_enc[b,p,:] + ad) + fb  — wave per p, lane-split-8
  float ad8[8], w8[8];
  const int a0 = lane * 8;
#pragma unroll
  for (int j = 0; j < 8; j++) { ad8[j] = ad_s[a0 + j]; w8[j] = faw[a0 + j]; }
  const float fb0 = fab[0];
  for (int p = wave; p < kP; p += 4) {
    const b16x8 rv = *(const b16x8*)(attn_enc_bf + ((long)(b * kP + p)) * kAttn + a0);
    float s = 0.f;
#pragma unroll
    for (int j = 0; j < 8; j++)
      s += w8[j] * fmaxf(bf2f(((const unsigned short*)&rv)[j]) + ad8[j], 0.f);
#pragma unroll
    for (int off = 32; off > 0; off >>= 1) s += __shfl_down(s, off, 64);
    if (lane == 0) e_sm[p] = s + fb0;
  }
  __syncthreads();

  // softmax over 196
  const float v = (tid < kP) ? e_sm[tid] : -3.0e38f;
  float m = v;
#pragma unroll
  for (int off = 32; off > 0; off >>= 1) m = fmaxf(m, __shfl_down(m, off, 64));
  if (lane == 0) red[wave] = m;
  __syncthreads();
  m = fmaxf(fmaxf(red[0], red[1]), fmaxf(red[2], red[3]));
  const float ex = (tid < kP) ? expf(v - m) : 0.f;
  float s = ex;
#pragma unroll
  for (int off = 32; off > 0; off >>= 1) s += __shfl_down(s, off, 64);
  if (lane == 0) red[wave] = s;
  __syncthreads();
  s = red[0] + red[1] + red[2] + red[3];
  __syncthreads();                 // red/e_sm reuse ordering
  const float alpha = ex / s;
  if (tid < kP) {
    e_sm[tid] = alpha;
    if (half == 0) alphas[((long)b * kT + t) * kP + tid] = alpha;
  }
  __syncthreads();

  // context slice: 1024 dims per half, 4 per thread
  const int e = half * 1024 + tid * 4;
  float a4[4] = {};
  if (SRC_BF16) {
    const unsigned short* base = (const unsigned short*)enc_ + (long)b * kP * kEnc + e;
    for (int p = 0; p < kP; p++) {
      const float a = e_sm[p];
      const b16x4 rv = *(const b16x4*)(base + (long)p * kEnc);
#pragma unroll
      for (int j = 0; j < 4; j++) a4[j] += a * bf2f(((const unsigned short*)&rv)[j]);
    }
  } else {
    const float* base = (const float*)enc_ + (long)b * kP * kEnc + e;
    for (int p = 0; p < kP; p++) {
      const float a = e_sm[p];
      const f32x4 rv = *(const f32x4*)(base + (long)p * kEnc);
#pragma unroll
      for (int j = 0; j < 4; j++) a4[j] += a * rv[j];
    }
  }
  u16x4 o;
#pragma unroll
  for (int j = 0; j < 4; j++) o[j] = f2bf(a4[j]);
  *(u16x4*)(ctx + (long)b * kEnc + e) = o;
}

// =========== gates GEMM, split-K x4: partial[z] = [emb|ctx|h] @ [Wih|Whh]^T (k in z-chunk) ====
__global__ __launch_bounds__(256) void gemm_gates(
    const unsigned short* __restrict__ embs_t, const unsigned short* __restrict__ ctx,
    const unsigned short* __restrict__ hbf, const unsigned short* __restrict__ Wih,
    const unsigned short* __restrict__ Whh, float* __restrict__ gates_part) {
  const int lane = threadIdx.x & 63;
  const int wave = threadIdx.x >> 6;
  const int wm = wave >> 1, wn = wave & 1;
  const int m0 = blockIdx.y * 64 + wm * 32;   // M=128
  const int n0 = blockIdx.x * 64 + wn * 32;   // N=2048
  const int z = blockIdx.z;                    // k-chunk of 768
  const int q = lane >> 4;
  const int l = lane & 15;
  f32x4 acc[2][2] = {};
  float* gout = gates_part + (long)z * kB * 2048;

  const int kbeg = z * 768, kend = kbeg + 768;
  for (int k0 = kbeg; k0 < kend; k0 += 32) {
    b16x8 af[2], wf[2];
#pragma unroll
    for (int i = 0; i < 2; i++) {
      const int r = m0 + 16 * i + l;
      const unsigned short* p;
      if (k0 < 512)        p = embs_t + (long)r * kEmb + k0;
      else if (k0 < 2560)  p = ctx + (long)r * kEnc + (k0 - 512);
      else                 p = hbf + (long)r * kDec + (k0 - 2560);
      af[i] = *(const b16x8*)(p + q * 8);
    }
#pragma unroll
    for (int j = 0; j < 2; j++) {
      const int r = n0 + 16 * j + l;
      const unsigned short* p;
      if (k0 < 2560) p = Wih + (long)r * 2560 + k0;
      else           p = Whh + (long)r * 512 + (k0 - 2560);
      wf[j] = *(const b16x8*)(p + q * 8);
    }
#pragma unroll
    for (int i = 0; i < 2; i++)
#pragma unroll
      for (int j = 0; j < 2; j++)
        acc[i][j] = __builtin_amdgcn_mfma_f32_16x16x32_bf16(af[i], wf[j], acc[i][j], 0, 0, 0);
  }
#pragma unroll
  for (int i = 0; i < 2; i++)
#pragma unroll
    for (int j = 0; j < 2; j++) {
      const int col = n0 + 16 * j + l;
#pragma unroll
      for (int r = 0; r < 4; r++) {
        const int row = m0 + 16 * i + q * 4 + r;
        gout[(long)row * 2048 + col] = acc[i][j][r];
      }
    }
}

// =========== LSTM pointwise: combine 4 split-K partials + bias, update c/h ===========
__global__ __launch_bounds__(256) void lstm_pw(
    const float* __restrict__ gp, const float* __restrict__ bsum,
    float* __restrict__ c, float* __restrict__ h, unsigned short* __restrict__ hbf) {
  const int idx = blockIdx.x * 256 + threadIdx.x;  // 0 .. 128*512-1
  const int b = idx >> 9, d = idx & 511;
  float g4[4];
#pragma unroll
  for (int g = 0; g < 4; g++) {
    const int col = g * 512 + d;
    float s = bsum[col];
#pragma unroll
    for (int z = 0; z < 4; z++) s += gp[(long)z * kB * 2048 + (long)b * 2048 + col];
    g4[g] = s;
  }
  const float si = 1.f / (1.f + expf(-g4[0]));
  const float sf = 1.f / (1.f + expf(-g4[1]));
  const float so = 1.f / (1.f + expf(-g4[3]));
  const float cn = sf * c[idx] + si * tanhf(g4[2]);
  const float hn = so * tanhf(cn);
  c[idx] = cn;
  h[idx] = hn;
  hbf[idx] = f2bf(hn);
}

// =========== prelude kernels ===========
template <bool SRC_BF16>
__global__ __launch_bounds__(256) void mean_kernel(
    const void* __restrict__ enc_, unsigned short* __restrict__ mean_bf) {
  const int b = blockIdx.x;
  const int e = threadIdx.x * 8;
  float acc[8] = {};
  if (SRC_BF16) {
    const unsigned short* base = (const unsigned short*)enc_ + (long)b * kP * kEnc + e;
    for (int p = 0; p < kP; p++) {
      const b16x8 v = *(const b16x8*)(base + (long)p * kEnc);
#pragma unroll
      for (int j = 0; j < 8; j++) acc[j] += bf2f(((const unsigned short*)&v)[j]);
    }
  } else {
    const float* base = (const float*)enc_ + (long)b * kP * kEnc + e;
    for (int p = 0; p < kP; p++) {
      const f32x4 lo = *(const f32x4*)(base + (long)p * kEnc);
      const f32x4 hi = *(const f32x4*)(base + (long)p * kEnc + 4);
#pragma unroll
      for (int j = 0; j < 4; j++) { acc[j] += lo[j]; acc[4 + j] += hi[j]; }
    }
  }
#pragma unroll
  for (int j = 0; j < 8; j++)
    mean_bf[(long)b * kEnc + e + j] = f2bf(acc[j] * (1.0f / 196.0f));
}

__global__ __launch_bounds__(256) void f32_to_bf16_vec(
    const float* __restrict__ src, unsigned short* __restrict__ dst, long n4) {
  for (long i = blockIdx.x * (long)blockDim.x + threadIdx.x; i < n4;
       i += (long)gridDim.x * blockDim.x) {
    const f32x4 v = *(const f32x4*)(src + i * 4);
    u16x4 o;
#pragma unroll
    for (int j = 0; j < 4; j++) o[j] = f2bf(v[j]);
    *(u16x4*)(dst + i * 4) = o;
  }
}

__global__ __launch_bounds__(256) void gather_emb(
    const float* __restrict__ embedding, const int* __restrict__ captions,
    unsigned short* __restrict__ embs) {
  const int r = blockIdx.x;           // t*128 + b
  const int t = r >> 7, b = r & 127;
  const int cap = captions[b * kT + t];
  const float* src = embedding + (long)cap * kEmb;
  unsigned short* dst = embs + (long)r * kEmb;
  for (int i = threadIdx.x; i < kEmb; i += 256) dst[i] = f2bf(src[i]);
}

__global__ void bias_sum_k(const float* __restrict__ b1, const float* __restrict__ b2,
                           float* __restrict__ o) {
  const int i = blockIdx.x * 256 + threadIdx.x;
  if (i < 2048) o[i] = b1[i] + b2[i];
}

// ---------------- host ----------------
extern "C" void kernel_launch(void* const* d_in, const int* in_sizes, int n_in,
                              void* d_out, int out_size, void* d_ws, size_t ws_size,
                              hipStream_t stream) {
  const float* enc = (const float*)d_in[0];
  const int* captions = (const int*)d_in[1];
  const float* embedding = (const float*)d_in[3];
  const float* eaw = (const float*)d_in[4];
  const float* eab = (const float*)d_in[5];
  const float* daw = (const float*)d_in[6];
  const float* dab = (const float*)d_in[7];
  const float* faw = (const float*)d_in[8];
  const float* fab = (const float*)d_in[9];
  const float* Wih = (const float*)d_in[10];
  const float* bih = (const float*)d_in[11];
  const float* Whh = (const float*)d_in[12];
  const float* bhh = (const float*)d_in[13];
  const float* ihw = (const float*)d_in[14];
  const float* ihb = (const float*)d_in[15];
  const float* icw = (const float*)d_in[16];
  const float* icb = (const float*)d_in[17];
  const float* fcw = (const float*)d_in[18];
  const float* fcb = (const float*)d_in[19];

  float* out = (float*)d_out;                        // outputs [B,T,VOCAB]
  float* alphas = out + (long)kB * kT * kVocab;      // alphas  [B,T,P]

  char* ws = (char*)d_ws;
  size_t off = 0;
  auto alloc = [&](size_t bytes) -> void* {
    void* p = ws + off;
    off = (off + bytes + 255) & ~(size_t)255;
    return p;
  };
  unsigned short* attn_enc_bf = (unsigned short*)alloc((size_t)kB * kP * kAttn * 2);
  unsigned short* Wih_bf = (unsigned short*)alloc((size_t)2048 * 2560 * 2);
  unsigned short* Whh_bf = (unsigned short*)alloc((size_t)2048 * 512 * 2);
  unsigned short* fcw_bf = (unsigned short*)alloc((size_t)kVocab * kDec * 2);
  unsigned short* eaw_bf = (unsigned short*)alloc((size_t)kAttn * kEnc * 2);
  unsigned short* daw_bf = (unsigned short*)alloc((size_t)kAttn * kDec * 2);
  unsigned short* ihw_bf = (unsigned short*)alloc((size_t)kDec * kEnc * 2);
  unsigned short* icw_bf = (unsigned short*)alloc((size_t)kDec * kEnc * 2);
  unsigned short* embs_bf = (unsigned short*)alloc((size_t)kT * kB * kEmb * 2);
  unsigned short* mean_bf = (unsigned short*)alloc((size_t)kB * kEnc * 2);
  float* h = (float*)alloc((size_t)kB * kDec * 4);
  float* c = (float*)alloc((size_t)kB * kDec * 4);
  unsigned short* h_bf = (unsigned short*)alloc((size_t)kB * kDec * 2);
  unsigned short* ctx_bf = (unsigned short*)alloc((size_t)kB * kEnc * 2);
  float* gates_part = (float*)alloc((size_t)4 * kB * 2048 * 4);
  float* bsum = (float*)alloc((size_t)2048 * 4);
  unsigned short* enc_bf = (unsigned short*)alloc((size_t)kB * kP * kEnc * 2);
  const bool have_enc_bf = (off <= ws_size);

  auto cvt = [&](const float* s, unsigned short* d, long n) {
    const long n4 = n / 4;
    long g = (n4 + 255) / 256;
    if (g > 2048) g = 2048;
    f32_to_bf16_vec<<<dim3((unsigned)g), dim3(256), 0, stream>>>(s, d, n4);
  };

  // ---- prelude
  cvt(eaw, eaw_bf, (long)kAttn * kEnc);
  cvt(daw, daw_bf, (long)kAttn * kDec);
  cvt(Wih, Wih_bf, (long)2048 * 2560);
  cvt(Whh, Whh_bf, (long)2048 * 512);
  cvt(fcw, fcw_bf, (long)kVocab * kDec);
  cvt(ihw, ihw_bf, (long)kDec * kEnc);
  cvt(icw, icw_bf, (long)kDec * kEnc);
  if (have_enc_bf) cvt(enc, enc_bf, (long)kB * kP * kEnc);
  bias_sum_k<<<8, 256, 0, stream>>>(bih, bhh, bsum);
  gather_emb<<<kT * kB, 256, 0, stream>>>(embedding, captions, embs_bf);
  if (have_enc_bf)
    mean_kernel<true><<<kB, 256, 0, stream>>>(enc_bf, mean_bf);
  else
    mean_kernel<false><<<kB, 256, 0, stream>>>(enc, mean_bf);

  gemm_bt<true, false><<<dim3(kDec / 64, kB / 64), 256, 0, stream>>>(
      mean_bf, ihw_bf, ihb, h, (unsigned short*)nullptr, kB, kDec, kEnc, kDec);
  gemm_bt<true, false><<<dim3(kDec / 64, kB / 64), 256, 0, stream>>>(
      mean_bf, icw_bf, icb, c, (unsigned short*)nullptr, kB, kDec, kEnc, kDec);
  cvt(h, h_bf, (long)kB * kDec);

  // attn_enc projection: [25088,2048] @ [512,2048]^T -> bf16 [25088,512]
  if (have_enc_bf)
    gemm128<true><<<dim3(kAttn / 128, (kB * kP) / 128), 256, 0, stream>>>(
        enc_bf, eaw_bf, eab, (float*)nullptr, attn_enc_bf, kB * kP, kAttn, kEnc, kAttn);
  else
    gemm_bt<false, true><<<dim3(kAttn / 64, (kB * kP) / 64), 256, 0, stream>>>(
        enc, eaw_bf, eab, (float*)nullptr, attn_enc_bf, kB * kP, kAttn, kEnc, kAttn);

  // ---- T sequential decode steps (4 kernels/step)
  for (int t = 0; t < kT; t++) {
    if (have_enc_bf)
      attn_step<true><<<dim3(kB, 2), 256, 0, stream>>>(
          enc_bf, attn_enc_bf, h_bf, daw_bf, dab, faw, fab, alphas, ctx_bf, t);
    else
      attn_step<false><<<dim3(kB, 2), 256, 0, stream>>>(
          enc, attn_enc_bf, h_bf, daw_bf, dab, faw, fab, alphas, ctx_bf, t);

    gemm_gates<<<dim3(2048 / 64, kB / 64, 4), 256, 0, stream>>>(
        embs_bf + (long)t * kB * kEmb, ctx_bf, h_bf, Wih_bf, Whh_bf, gates_part);

    lstm_pw<<<(kB * kDec) / 256, 256, 0, stream>>>(gates_part, bsum, c, h, h_bf);

    gemm_bt<true, false><<<dim3((kVocab + 63) / 64, kB / 64), 256, 0, stream>>>(
        h_bf, fcw_bf, fcb, out + (long)t * kVocab, (unsigned short*)nullptr,
        kB, kVocab, kDec, (long)kT * kVocab);
  }
}

// Round 3
// 2449.271 us; speedup vs baseline: 1.5415x; 1.0301x over previous
//
#include <hip/hip_runtime.h>

// ---------------- problem constants ----------------
constexpr int kB = 128, kP = 196, kT = 20;
constexpr int kVocab = 10000, kEnc = 2048, kEmb = 512, kDec = 512, kAttn = 512;

typedef __bf16 b16x8 __attribute__((ext_vector_type(8)));
typedef __bf16 b16x4 __attribute__((ext_vector_type(4)));
typedef float f32x4 __attribute__((ext_vector_type(4)));
typedef unsigned short u16x4 __attribute__((ext_vector_type(4)));

__device__ __forceinline__ unsigned short f2bf(float f) {
  unsigned int u = __float_as_uint(f);
  u += 0x7fffu + ((u >> 16) & 1u);          // RNE (inputs finite)
  return (unsigned short)(u >> 16);
}
__device__ __forceinline__ float bf2f(unsigned short h) {
  return __uint_as_float(((unsigned int)h) << 16);
}

__device__ __forceinline__ void async16(const void* g, void* l) {
  __builtin_amdgcn_global_load_lds(
      (const __attribute__((address_space(1))) unsigned int*)g,
      (__attribute__((address_space(3))) unsigned int*)l, 16, 0, 0);
}

// =========== attn_enc projection GEMM: Cb[M,512] = A[M,2048] @ W[512,2048]^T + bias ===========
// Tile 128M x 64N, BK=32. A staged in LDS CHUNK-MAJOR (slot = chunk*128+row, 16B slots):
// fragment reads hit 16 consecutive 16B slots -> 2-way bank alias only (free).
// B (2MB, L2-resident) loaded direct to VGPRs. grid = (512/64, M/128) = (8, 196).
__global__ __launch_bounds__(256) void gemm_ae(
    const unsigned short* __restrict__ A, const unsigned short* __restrict__ W,
    const float* __restrict__ bias, unsigned short* __restrict__ Cb, int M, int K) {
  __shared__ unsigned short sA[128 * 32];   // 8 KB
  const int tid = threadIdx.x;
  const int lane = tid & 63, wave = tid >> 6;
  const int m0 = blockIdx.y * 128;
  const int n0 = blockIdx.x * 64;
  const int q = lane >> 4, l = lane & 15;
  const int ch0 = tid >> 7, row0 = tid & 127;    // slot tid
  f32x4 acc[2][4] = {};

  for (int k0 = 0; k0 < K; k0 += 32) {
    // stage A chunk-major: slot s -> logical (row=s&127, chunk=s>>7)
    async16(A + (long)(m0 + row0) * K + k0 + ch0 * 8, &sA[(ch0 * 128 + row0) * 8]);
    async16(A + (long)(m0 + row0) * K + k0 + (ch0 + 2) * 8, &sA[((ch0 + 2) * 128 + row0) * 8]);
    // B fragments direct (issue before barrier so latency overlaps the LDS drain)
    b16x8 bf4[4];
#pragma unroll
    for (int j = 0; j < 4; j++)
      bf4[j] = *(const b16x8*)(W + (long)(n0 + 16 * j + l) * K + k0 + q * 8);
    __syncthreads();
    b16x8 af[2];
#pragma unroll
    for (int i = 0; i < 2; i++)
      af[i] = *(const b16x8*)&sA[(q * 128 + wave * 32 + 16 * i + l) * 8];
#pragma unroll
    for (int i = 0; i < 2; i++)
#pragma unroll
      for (int j = 0; j < 4; j++)
        acc[i][j] = __builtin_amdgcn_mfma_f32_16x16x32_bf16(af[i], bf4[j], acc[i][j], 0, 0, 0);
    __syncthreads();
  }

#pragma unroll
  for (int i = 0; i < 2; i++)
#pragma unroll
    for (int j = 0; j < 4; j++) {
      const int col = n0 + 16 * j + l;
      const float bv = bias[col];
#pragma unroll
      for (int r = 0; r < 4; r++) {
        const int row = m0 + wave * 32 + 16 * i + q * 4 + r;
        Cb[(long)row * 512 + col] = f2bf(acc[i][j][r] + bv);
      }
    }
}

// =========== generic small bf16 MFMA GEMM (64x64 tile, direct loads) — prelude/fallback ======
template <bool A_BF16, bool OUT_BF16>
__global__ __launch_bounds__(256) void gemm_bt(
    const void* __restrict__ A_, const unsigned short* __restrict__ W,
    const float* __restrict__ bias, float* __restrict__ C,
    unsigned short* __restrict__ Cb, int M, int N, int K, long ldc) {
  const int lane = threadIdx.x & 63;
  const int wave = threadIdx.x >> 6;
  const int wm = wave >> 1, wn = wave & 1;
  const int m0 = blockIdx.y * 64 + wm * 32;
  const int n0 = blockIdx.x * 64 + wn * 32;
  const int q = lane >> 4;
  const int l = lane & 15;
  f32x4 acc[2][2] = {};
  const unsigned short* Ab = (const unsigned short*)A_;
  const float* Af = (const float*)A_;

  for (int k0 = 0; k0 < K; k0 += 32) {
    const int ka = k0 + q * 8;
    b16x8 af[2], wf[2];
#pragma unroll
    for (int i = 0; i < 2; i++) {
      int r = m0 + 16 * i + l;
      if (r >= M) r = M - 1;
      if (A_BF16) {
        af[i] = *(const b16x8*)(Ab + (long)r * K + ka);
      } else {
        const float* p = Af + (long)r * K + ka;
        const f32x4 lo = *(const f32x4*)p;
        const f32x4 hi = *(const f32x4*)(p + 4);
        b16x8 t;
#pragma unroll
        for (int j = 0; j < 4; j++) {
          ((unsigned short*)&t)[j] = f2bf(lo[j]);
          ((unsigned short*)&t)[4 + j] = f2bf(hi[j]);
        }
        af[i] = t;
      }
    }
#pragma unroll
    for (int j = 0; j < 2; j++) {
      int r = n0 + 16 * j + l;
      if (r >= N) r = N - 1;
      wf[j] = *(const b16x8*)(W + (long)r * K + ka);
    }
#pragma unroll
    for (int i = 0; i < 2; i++)
#pragma unroll
      for (int j = 0; j < 2; j++)
        acc[i][j] = __builtin_amdgcn_mfma_f32_16x16x32_bf16(af[i], wf[j], acc[i][j], 0, 0, 0);
  }

#pragma unroll
  for (int i = 0; i < 2; i++)
#pragma unroll
    for (int j = 0; j < 2; j++) {
      const int col = n0 + 16 * j + l;
      if (col >= N) continue;
      const float bv = bias ? bias[col] : 0.0f;
#pragma unroll
      for (int r = 0; r < 4; r++) {
        const int row = m0 + 16 * i + q * 4 + r;
        if (row >= M) continue;
        const float v = acc[i][j][r] + bv;
        if (OUT_BF16) Cb[(long)row * ldc + col] = f2bf(v);
        else          C[(long)row * ldc + col] = v;
      }
    }
}

// =========== fused [ad = h@daw^T + dab] || [preds = h@fcw^T + fcb] ===========
// Both depend only on the fresh h. K=512, M=128, BK=64 (2x outstanding loads).
// blocks 0..15: ad (8x2 tiles of 64). blocks 16..329: fc (157x2 tiles of 64).
__global__ __launch_bounds__(256) void adfc_kernel(
    const unsigned short* __restrict__ h_bf,
    const unsigned short* __restrict__ daw, const float* __restrict__ dab,
    float* __restrict__ ad_out,
    const unsigned short* __restrict__ fcw, const float* __restrict__ fcb,
    float* __restrict__ preds, long pred_ld) {
  const int blk = blockIdx.x;
  const unsigned short* W;
  const float* bias;
  float* out;
  long ldc;
  int N, m0, n0;
  if (blk < 16) {
    if (!ad_out) return;
    W = daw; bias = dab; out = ad_out; ldc = 512; N = 512;
    n0 = (blk & 7) * 64; m0 = (blk >> 3) * 64;
  } else {
    if (!preds) return;
    const int idx = blk - 16;
    W = fcw; bias = fcb; out = preds; ldc = pred_ld; N = kVocab;
    n0 = (idx % 157) * 64; m0 = (idx / 157) * 64;
  }
  const int lane = threadIdx.x & 63, wave = threadIdx.x >> 6;
  const int wm = wave >> 1, wn = wave & 1;
  const int q = lane >> 4, l = lane & 15;
  const int mi = m0 + wm * 32, ni = n0 + wn * 32;
  f32x4 acc[2][2] = {};

  for (int k0 = 0; k0 < 512; k0 += 64) {
    b16x8 af[2][2], wf[2][2];
#pragma unroll
    for (int u = 0; u < 2; u++) {
      const int ka = k0 + u * 32 + q * 8;
#pragma unroll
      for (int i = 0; i < 2; i++)
        af[u][i] = *(const b16x8*)(h_bf + (long)(mi + 16 * i + l) * 512 + ka);
#pragma unroll
      for (int j = 0; j < 2; j++) {
        int r = ni + 16 * j + l;
        if (r >= N) r = N - 1;
        wf[u][j] = *(const b16x8*)(W + (long)r * 512 + ka);
      }
    }
#pragma unroll
    for (int u = 0; u < 2; u++)
#pragma unroll
      for (int i = 0; i < 2; i++)
#pragma unroll
        for (int j = 0; j < 2; j++)
          acc[i][j] = __builtin_amdgcn_mfma_f32_16x16x32_bf16(af[u][i], wf[u][j], acc[i][j], 0, 0, 0);
  }
#pragma unroll
  for (int i = 0; i < 2; i++)
#pragma unroll
    for (int j = 0; j < 2; j++) {
      const int col = ni + 16 * j + l;
      if (col >= N) continue;
      const float bv = bias[col];
#pragma unroll
      for (int r = 0; r < 4; r++) {
        const int row = mi + 16 * i + q * 4 + r;
        out[(long)row * ldc + col] = acc[i][j][r] + bv;
      }
    }
}

// =========== attention: energy + softmax + context (ad precomputed) ===========
// grid (kB, 2): each half covers 1024 context dims; context p-split x2 in-block.
template <bool SRC_BF16>
__global__ __launch_bounds__(256) void attn2(
    const void* __restrict__ enc_, const unsigned short* __restrict__ attn_enc_bf,
    const float* __restrict__ ad_g, const float* __restrict__ faw,
    const float* __restrict__ fab, float* __restrict__ alphas,
    unsigned short* __restrict__ ctx, int t) {
  const int b = blockIdx.x;
  const int half = blockIdx.y;
  const int tid = threadIdx.x;
  const int lane = tid & 63, wave = tid >> 6;
  __shared__ float ad_s[512];
  __shared__ float e_sm[kP];
  __shared__ float red[4];
  __shared__ float cred[128][8];

  ad_s[tid] = ad_g[b * kAttn + tid];
  ad_s[tid + 256] = ad_g[b * kAttn + tid + 256];
  __syncthreads();

  // energy[p] = fw . relu(attn_enc[b,p,:] + ad) + fb  — wave per p, lane-split-8
  float ad8[8], w8[8];
  const int a0 = lane * 8;
#pragma unroll
  for (int j = 0; j < 8; j++) { ad8[j] = ad_s[a0 + j]; w8[j] = faw[a0 + j]; }
  const float fb0 = fab[0];
  for (int p = wave; p < kP; p += 4) {
    const b16x8 rv = *(const b16x8*)(attn_enc_bf + ((long)(b * kP + p)) * kAttn + a0);
    float s = 0.f;
#pragma unroll
    for (int j = 0; j < 8; j++)
      s += w8[j] * fmaxf(bf2f(((const unsigned short*)&rv)[j]) + ad8[j], 0.f);
#pragma unroll
    for (int off = 32; off > 0; off >>= 1) s += __shfl_down(s, off, 64);
    if (lane == 0) e_sm[p] = s + fb0;
  }
  __syncthreads();

  // softmax over 196
  const float v = (tid < kP) ? e_sm[tid] : -3.0e38f;
  float m = v;
#pragma unroll
  for (int off = 32; off > 0; off >>= 1) m = fmaxf(m, __shfl_down(m, off, 64));
  if (lane == 0) red[wave] = m;
  __syncthreads();
  m = fmaxf(fmaxf(red[0], red[1]), fmaxf(red[2], red[3]));
  const float ex = (tid < kP) ? expf(v - m) : 0.f;
  float s = ex;
#pragma unroll
  for (int off = 32; off > 0; off >>= 1) s += __shfl_down(s, off, 64);
  if (lane == 0) red[wave] = s;
  __syncthreads();
  s = red[0] + red[1] + red[2] + red[3];
  __syncthreads();
  const float alpha = ex / s;
  if (tid < kP) {
    e_sm[tid] = alpha;
    if (half == 0) alphas[((long)b * kT + t) * kP + tid] = alpha;
  }
  __syncthreads();

  // context: this half covers dims [half*1024, half*1024+1024); 8 dims/thread, p-split x2
  const int pg = tid >> 7, th = tid & 127;
  const int e = half * 1024 + th * 8;
  float a8[8] = {};
  if (SRC_BF16) {
    const unsigned short* base = (const unsigned short*)enc_ + (long)b * kP * kEnc + e;
    const int pbeg = pg * 98;
#pragma unroll 2
    for (int p = pbeg; p < pbeg + 98; p++) {
      const float a = e_sm[p];
      const b16x8 rv = *(const b16x8*)(base + (long)p * kEnc);
#pragma unroll
      for (int j = 0; j < 8; j++) a8[j] += a * bf2f(((const unsigned short*)&rv)[j]);
    }
  } else {
    const float* base = (const float*)enc_ + (long)b * kP * kEnc + e;
    const int pbeg = pg * 98;
#pragma unroll 2
    for (int p = pbeg; p < pbeg + 98; p++) {
      const float a = e_sm[p];
      const f32x4 lo = *(const f32x4*)(base + (long)p * kEnc);
      const f32x4 hi = *(const f32x4*)(base + (long)p * kEnc + 4);
#pragma unroll
      for (int j = 0; j < 4; j++) { a8[j] += a * lo[j]; a8[4 + j] += a * hi[j]; }
    }
  }
  if (pg == 1) {
#pragma unroll
    for (int j = 0; j < 8; j++) cred[th][j] = a8[j];
  }
  __syncthreads();
  if (pg == 0) {
    u16x4 o0, o1;
#pragma unroll
    for (int j = 0; j < 4; j++) {
      o0[j] = f2bf(a8[j] + cred[th][j]);
      o1[j] = f2bf(a8[4 + j] + cred[th][4 + j]);
    }
    *(u16x4*)(ctx + (long)b * kEnc + e) = o0;
    *(u16x4*)(ctx + (long)b * kEnc + e + 4) = o1;
  }
}

// =========== gates GEMM, split-K x4 ===========
__global__ __launch_bounds__(256) void gemm_gates(
    const unsigned short* __restrict__ embs_t, const unsigned short* __restrict__ ctx,
    const unsigned short* __restrict__ hbf, const unsigned short* __restrict__ Wih,
    const unsigned short* __restrict__ Whh, float* __restrict__ gates_part) {
  const int lane = threadIdx.x & 63;
  const int wave = threadIdx.x >> 6;
  const int wm = wave >> 1, wn = wave & 1;
  const int m0 = blockIdx.y * 64 + wm * 32;   // M=128
  const int n0 = blockIdx.x * 64 + wn * 32;   // N=2048
  const int z = blockIdx.z;                    // k-chunk of 768
  const int q = lane >> 4;
  const int l = lane & 15;
  f32x4 acc[2][2] = {};
  float* gout = gates_part + (long)z * kB * 2048;

  const int kbeg = z * 768, kend = kbeg + 768;
  for (int k0 = kbeg; k0 < kend; k0 += 32) {
    b16x8 af[2], wf[2];
#pragma unroll
    for (int i = 0; i < 2; i++) {
      const int r = m0 + 16 * i + l;
      const unsigned short* p;
      if (k0 < 512)        p = embs_t + (long)r * kEmb + k0;
      else if (k0 < 2560)  p = ctx + (long)r * kEnc + (k0 - 512);
      else                 p = hbf + (long)r * kDec + (k0 - 2560);
      af[i] = *(const b16x8*)(p + q * 8);
    }
#pragma unroll
    for (int j = 0; j < 2; j++) {
      const int r = n0 + 16 * j + l;
      const unsigned short* p;
      if (k0 < 2560) p = Wih + (long)r * 2560 + k0;
      else           p = Whh + (long)r * 512 + (k0 - 2560);
      wf[j] = *(const b16x8*)(p + q * 8);
    }
#pragma unroll
    for (int i = 0; i < 2; i++)
#pragma unroll
      for (int j = 0; j < 2; j++)
        acc[i][j] = __builtin_amdgcn_mfma_f32_16x16x32_bf16(af[i], wf[j], acc[i][j], 0, 0, 0);
  }
#pragma unroll
  for (int i = 0; i < 2; i++)
#pragma unroll
    for (int j = 0; j < 2; j++) {
      const int col = n0 + 16 * j + l;
#pragma unroll
      for (int r = 0; r < 4; r++) {
        const int row = m0 + 16 * i + q * 4 + r;
        gout[(long)row * 2048 + col] = acc[i][j][r];
      }
    }
}

// =========== LSTM pointwise: combine 4 split-K partials + bias, update c/h ===========
__global__ __launch_bounds__(256) void lstm_pw(
    const float* __restrict__ gp, const float* __restrict__ bsum,
    float* __restrict__ c, float* __restrict__ h, unsigned short* __restrict__ hbf) {
  const int idx = blockIdx.x * 256 + threadIdx.x;  // 0 .. 128*512-1
  const int b = idx >> 9, d = idx & 511;
  float g4[4];
#pragma unroll
  for (int g = 0; g < 4; g++) {
    const int col = g * 512 + d;
    float s = bsum[col];
#pragma unroll
    for (int z = 0; z < 4; z++) s += gp[(long)z * kB * 2048 + (long)b * 2048 + col];
    g4[g] = s;
  }
  const float si = 1.f / (1.f + expf(-g4[0]));
  const float sf = 1.f / (1.f + expf(-g4[1]));
  const float so = 1.f / (1.f + expf(-g4[3]));
  const float cn = sf * c[idx] + si * tanhf(g4[2]);
  const float hn = so * tanhf(cn);
  c[idx] = cn;
  h[idx] = hn;
  hbf[idx] = f2bf(hn);
}

// =========== prelude kernels ===========
template <bool SRC_BF16>
__global__ __launch_bounds__(256) void mean_kernel(
    const void* __restrict__ enc_, unsigned short* __restrict__ mean_bf) {
  const int b = blockIdx.x;
  const int e = threadIdx.x * 8;
  float acc[8] = {};
  if (SRC_BF16) {
    const unsigned short* base = (const unsigned short*)enc_ + (long)b * kP * kEnc + e;
    for (int p = 0; p < kP; p++) {
      const b16x8 v = *(const b16x8*)(base + (long)p * kEnc);
#pragma unroll
      for (int j = 0; j < 8; j++) acc[j] += bf2f(((const unsigned short*)&v)[j]);
    }
  } else {
    const float* base = (const float*)enc_ + (long)b * kP * kEnc + e;
    for (int p = 0; p < kP; p++) {
      const f32x4 lo = *(const f32x4*)(base + (long)p * kEnc);
      const f32x4 hi = *(const f32x4*)(base + (long)p * kEnc + 4);
#pragma unroll
      for (int j = 0; j < 4; j++) { acc[j] += lo[j]; acc[4 + j] += hi[j]; }
    }
  }
#pragma unroll
  for (int j = 0; j < 8; j++)
    mean_bf[(long)b * kEnc + e + j] = f2bf(acc[j] * (1.0f / 196.0f));
}

__global__ __launch_bounds__(256) void f32_to_bf16_vec(
    const float* __restrict__ src, unsigned short* __restrict__ dst, long n4) {
  for (long i = blockIdx.x * (long)blockDim.x + threadIdx.x; i < n4;
       i += (long)gridDim.x * blockDim.x) {
    const f32x4 v = *(const f32x4*)(src + i * 4);
    u16x4 o;
#pragma unroll
    for (int j = 0; j < 4; j++) o[j] = f2bf(v[j]);
    *(u16x4*)(dst + i * 4) = o;
  }
}

__global__ __launch_bounds__(256) void gather_emb(
    const float* __restrict__ embedding, const int* __restrict__ captions,
    unsigned short* __restrict__ embs) {
  const int r = blockIdx.x;           // t*128 + b
  const int t = r >> 7, b = r & 127;
  const int cap = captions[b * kT + t];
  const float* src = embedding + (long)cap * kEmb;
  unsigned short* dst = embs + (long)r * kEmb;
  for (int i = threadIdx.x; i < kEmb; i += 256) dst[i] = f2bf(src[i]);
}

__global__ void bias_sum_k(const float* __restrict__ b1, const float* __restrict__ b2,
                           float* __restrict__ o) {
  const int i = blockIdx.x * 256 + threadIdx.x;
  if (i < 2048) o[i] = b1[i] + b2[i];
}

// ---------------- host ----------------
extern "C" void kernel_launch(void* const* d_in, const int* in_sizes, int n_in,
                              void* d_out, int out_size, void* d_ws, size_t ws_size,
                              hipStream_t stream) {
  const float* enc = (const float*)d_in[0];
  const int* captions = (const int*)d_in[1];
  const float* embedding = (const float*)d_in[3];
  const float* eaw = (const float*)d_in[4];
  const float* eab = (const float*)d_in[5];
  const float* daw = (const float*)d_in[6];
  const float* dab = (const float*)d_in[7];
  const float* faw = (const float*)d_in[8];
  const float* fab = (const float*)d_in[9];
  const float* Wih = (const float*)d_in[10];
  const float* bih = (const float*)d_in[11];
  const float* Whh = (const float*)d_in[12];
  const float* bhh = (const float*)d_in[13];
  const float* ihw = (const float*)d_in[14];
  const float* ihb = (const float*)d_in[15];
  const float* icw = (const float*)d_in[16];
  const float* icb = (const float*)d_in[17];
  const float* fcw = (const float*)d_in[18];
  const float* fcb = (const float*)d_in[19];

  float* out = (float*)d_out;                        // outputs [B,T,VOCAB]
  float* alphas = out + (long)kB * kT * kVocab;      // alphas  [B,T,P]

  char* ws = (char*)d_ws;
  size_t off = 0;
  auto alloc = [&](size_t bytes) -> void* {
    void* p = ws + off;
    off = (off + bytes + 255) & ~(size_t)255;
    return p;
  };
  unsigned short* attn_enc_bf = (unsigned short*)alloc((size_t)kB * kP * kAttn * 2);
  unsigned short* Wih_bf = (unsigned short*)alloc((size_t)2048 * 2560 * 2);
  unsigned short* Whh_bf = (unsigned short*)alloc((size_t)2048 * 512 * 2);
  unsigned short* fcw_bf = (unsigned short*)alloc((size_t)kVocab * kDec * 2);
  unsigned short* eaw_bf = (unsigned short*)alloc((size_t)kAttn * kEnc * 2);
  unsigned short* daw_bf = (unsigned short*)alloc((size_t)kAttn * kDec * 2);
  unsigned short* ihw_bf = (unsigned short*)alloc((size_t)kDec * kEnc * 2);
  unsigned short* icw_bf = (unsigned short*)alloc((size_t)kDec * kEnc * 2);
  unsigned short* embs_bf = (unsigned short*)alloc((size_t)kT * kB * kEmb * 2);
  unsigned short* mean_bf = (unsigned short*)alloc((size_t)kB * kEnc * 2);
  float* h = (float*)alloc((size_t)kB * kDec * 4);
  float* c = (float*)alloc((size_t)kB * kDec * 4);
  unsigned short* h_bf = (unsigned short*)alloc((size_t)kB * kDec * 2);
  float* ad_buf = (float*)alloc((size_t)kB * kAttn * 4);
  unsigned short* ctx_bf = (unsigned short*)alloc((size_t)kB * kEnc * 2);
  float* gates_part = (float*)alloc((size_t)4 * kB * 2048 * 4);
  float* bsum = (float*)alloc((size_t)2048 * 4);
  unsigned short* enc_bf = (unsigned short*)alloc((size_t)kB * kP * kEnc * 2);
  const bool have_enc_bf = (off <= ws_size);

  auto cvt = [&](const float* s, unsigned short* d, long n) {
    const long n4 = n / 4;
    long g = (n4 + 255) / 256;
    if (g > 2048) g = 2048;
    f32_to_bf16_vec<<<dim3((unsigned)g), dim3(256), 0, stream>>>(s, d, n4);
  };

  // ---- prelude
  cvt(eaw, eaw_bf, (long)kAttn * kEnc);
  cvt(daw, daw_bf, (long)kAttn * kDec);
  cvt(Wih, Wih_bf, (long)2048 * 2560);
  cvt(Whh, Whh_bf, (long)2048 * 512);
  cvt(fcw, fcw_bf, (long)kVocab * kDec);
  cvt(ihw, ihw_bf, (long)kDec * kEnc);
  cvt(icw, icw_bf, (long)kDec * kEnc);
  if (have_enc_bf) cvt(enc, enc_bf, (long)kB * kP * kEnc);
  bias_sum_k<<<8, 256, 0, stream>>>(bih, bhh, bsum);
  gather_emb<<<kT * kB, 256, 0, stream>>>(embedding, captions, embs_bf);
  if (have_enc_bf)
    mean_kernel<true><<<kB, 256, 0, stream>>>(enc_bf, mean_bf);
  else
    mean_kernel<false><<<kB, 256, 0, stream>>>(enc, mean_bf);

  gemm_bt<true, false><<<dim3(kDec / 64, kB / 64), 256, 0, stream>>>(
      mean_bf, ihw_bf, ihb, h, (unsigned short*)nullptr, kB, kDec, kEnc, kDec);
  gemm_bt<true, false><<<dim3(kDec / 64, kB / 64), 256, 0, stream>>>(
      mean_bf, icw_bf, icb, c, (unsigned short*)nullptr, kB, kDec, kEnc, kDec);
  cvt(h, h_bf, (long)kB * kDec);

  // attn_enc projection: [25088,2048] @ [512,2048]^T -> bf16 [25088,512]
  if (have_enc_bf)
    gemm_ae<<<dim3(kAttn / 64, (kB * kP) / 128), 256, 0, stream>>>(
        enc_bf, eaw_bf, eab, attn_enc_bf, kB * kP, kEnc);
  else
    gemm_bt<false, true><<<dim3(kAttn / 64, (kB * kP) / 64), 256, 0, stream>>>(
        enc, eaw_bf, eab, (float*)nullptr, attn_enc_bf, kB * kP, kAttn, kEnc, kAttn);

  // ---- T sequential decode steps
  // Step t: [ad(h_t) || preds_{t-1}(h_t)] -> attn -> gates -> lstm (h_{t+1})
  for (int t = 0; t < kT; t++) {
    adfc_kernel<<<330, 256, 0, stream>>>(
        h_bf, daw_bf, dab, ad_buf, fcw_bf, fcb,
        (t == 0) ? (float*)nullptr : out + (long)(t - 1) * kVocab, (long)kT * kVocab);

    if (have_enc_bf)
      attn2<true><<<dim3(kB, 2), 256, 0, stream>>>(
          enc_bf, attn_enc_bf, ad_buf, faw, fab, alphas, ctx_bf, t);
    else
      attn2<false><<<dim3(kB, 2), 256, 0, stream>>>(
          enc, attn_enc_bf, ad_buf, faw, fab, alphas, ctx_bf, t);

    gemm_gates<<<dim3(2048 / 64, kB / 64, 4), 256, 0, stream>>>(
        embs_bf + (long)t * kB * kEmb, ctx_bf, h_bf, Wih_bf, Whh_bf, gates_part);

    lstm_pw<<<(kB * kDec) / 256, 256, 0, stream>>>(gates_part, bsum, c, h, h_bf);
  }
  // final preds_19 = fc(h_20)
  adfc_kernel<<<330, 256, 0, stream>>>(
      h_bf, daw_bf, dab, (float*)nullptr, fcw_bf, fcb,
      out + (long)19 * kVocab, (long)kT * kVocab);
}